// Round 6
// baseline (101.417 us; speedup 1.0000x reference)
//
#include <hip/hip_runtime.h>

#define Bv 16
#define Cv 64
#define Sv 2048
#define NSEG 64           // pli segments
#define SSEG 32           // samples per pli segment
#define ROWS 68           // pli LDS row stride in floats (64 ch + 4 pad)

// Forward DIF butterfly: u' = u+v ; v' = (u-v)*w
__device__ __forceinline__ void bf_f(float2& u, float2& v, const float2 w) {
    const float dr = u.x - v.x, di = u.y - v.y;
    u.x += v.x; u.y += v.y;
    v.x = dr * w.x - di * w.y;
    v.y = dr * w.y + di * w.x;
}
// Inverse DIT butterfly: v' = v*conj(w) ; u' = u+v' ; l' = u-v'
__device__ __forceinline__ void bf_i(float2& u, float2& v, const float2 w) {
    const float vr = v.x * w.x + v.y * w.y;
    const float vi = v.y * w.x - v.x * w.y;
    v.x = u.x - vr; v.y = u.y - vi;
    u.x += vr; u.y += vi;
}
__device__ __forceinline__ float2 csq(const float2 a) {
    return make_float2(a.x * a.x - a.y * a.y, 2.0f * a.x * a.y);
}
__device__ __forceinline__ float2 cm1(const float2 a) {   // a * e^{-i pi/4}
    const float cq = 0.70710678118654752f;
    return make_float2(cq * (a.x + a.y), cq * (a.y - a.x));
}
__device__ __forceinline__ float2 cmi(const float2 a) {   // a * e^{-i pi/2}
    return make_float2(a.y, -a.x);
}

// ---------------------------------------------------------------------------
// Kernel 1: paired-channel Hilbert transform, register-grouped FFT with
// register-derived twiddles (no LDS twiddle table).
//   z = x_a + i*x_b ; w = ifft(h .* fft(z)) ; H(x_a)=Im(w)-x_b ; H(x_b)=x_a-Re(w)
// Twiddle identity: w(half, pos) = exp(-i*pi*pos/half); for a stage group with
// pos = r + 32k (or r + 256k): w = base(r) * e^{-i*pi*k/4}; next half uses
// base^2. Verified equal to the round-4 table indices Wt[half+pos].
// One block per channel pair (512 blocks).
// ---------------------------------------------------------------------------
__global__ __launch_bounds__(256) void hilbert_kernel(const float* __restrict__ x,
                                                      float* __restrict__ y) {
    __shared__ float2 zz[Sv];     // 16 KB
    const int t = threadIdx.x;
    const int c0 = blockIdx.x * 2;
    const float* x0 = x + (size_t)c0 * Sv;
    const float* x1 = x0 + Sv;

    const float PI = 3.14159265358979323846f;
    float2 bA4, bB4, bC2;
    sincosf(-PI * (float)t * (1.0f / 1024.0f), &bA4.y, &bA4.x);        // exp(-i pi t/1024)
    sincosf(-PI * (float)(t & 31) * (1.0f / 128.0f), &bB4.y, &bB4.x);  // exp(-i pi r/128)
    sincosf(-PI * (float)(t & 7) * (1.0f / 16.0f), &bC2.y, &bC2.x);    // exp(-i pi r/16)
    const float2 bA2 = csq(bA4), bA1 = csq(bA2);
    const float2 bB2 = csq(bB4), bB1 = csq(bB2);
    const float2 bC1 = csq(bC2);

    float2 z[8];
    #pragma unroll
    for (int k = 0; k < 8; ++k)
        z[k] = make_float2(x0[t + 256 * k], x1[t + 256 * k]);

    // ---- fwd halves 1024,512,256 (stride 256; n_k = t + 256k) ----
    {
        const float2 w1 = cm1(bA4);
        bf_f(z[0], z[4], bA4);      bf_f(z[1], z[5], w1);
        bf_f(z[2], z[6], cmi(bA4)); bf_f(z[3], z[7], cmi(w1));
        const float2 wB = cmi(bA2);
        bf_f(z[0], z[2], bA2); bf_f(z[1], z[3], wB);
        bf_f(z[4], z[6], bA2); bf_f(z[5], z[7], wB);
        bf_f(z[0], z[1], bA1); bf_f(z[2], z[3], bA1);
        bf_f(z[4], z[5], bA1); bf_f(z[6], z[7], bA1);
    }
    #pragma unroll
    for (int k = 0; k < 8; ++k) zz[t + 256 * k] = z[k];
    __syncthreads();

    // ---- fwd halves 128,64,32 (stride 32) ----
    {
        const int r = t & 31, base = (t >> 5) * 256 + r;
        #pragma unroll
        for (int k = 0; k < 8; ++k) z[k] = zz[base + 32 * k];
        const float2 w1 = cm1(bB4);
        bf_f(z[0], z[4], bB4);      bf_f(z[1], z[5], w1);
        bf_f(z[2], z[6], cmi(bB4)); bf_f(z[3], z[7], cmi(w1));
        const float2 wB = cmi(bB2);
        bf_f(z[0], z[2], bB2); bf_f(z[1], z[3], wB);
        bf_f(z[4], z[6], bB2); bf_f(z[5], z[7], wB);
        bf_f(z[0], z[1], bB1); bf_f(z[2], z[3], bB1);
        bf_f(z[4], z[5], bB1); bf_f(z[6], z[7], bB1);
        #pragma unroll
        for (int k = 0; k < 8; ++k) zz[base + 32 * k] = z[k];
    }
    __syncthreads();

    // ---- fwd halves 16,8 (stride 8; two 4-sets) ----
    {
        const int r = t & 7, base0 = (t >> 3) * 32 + r, base1 = base0 + 1024;
        #pragma unroll
        for (int k = 0; k < 4; ++k) { z[k] = zz[base0 + 8 * k]; z[4 + k] = zz[base1 + 8 * k]; }
        const float2 wB = cmi(bC2);
        bf_f(z[0], z[2], bC2); bf_f(z[1], z[3], wB);
        bf_f(z[4], z[6], bC2); bf_f(z[5], z[7], wB);
        bf_f(z[0], z[1], bC1); bf_f(z[2], z[3], bC1);
        bf_f(z[4], z[5], bC1); bf_f(z[6], z[7], bC1);
        #pragma unroll
        for (int k = 0; k < 4; ++k) { zz[base0 + 8 * k] = z[k]; zz[base1 + 8 * k] = z[4 + k]; }
    }
    __syncthreads();

    // ---- fused: fwd 4,2,1 ; Hilbert filter * 1/N ; inv 1,2,4 ----
    {
        const int base = 8 * t;
        #pragma unroll
        for (int k = 0; k < 8; ++k) z[k] = zz[base + k];
        const float cq = 0.70710678118654752f;
        const float2 W1  = make_float2(1.0f, 0.0f);
        const float2 W41 = make_float2(cq, -cq);
        const float2 W42 = make_float2(0.0f, -1.0f);
        const float2 W43 = make_float2(-cq, -cq);
        bf_f(z[0], z[4], W1);  bf_f(z[1], z[5], W41);
        bf_f(z[2], z[6], W42); bf_f(z[3], z[7], W43);
        bf_f(z[0], z[2], W1); bf_f(z[1], z[3], W42);
        bf_f(z[4], z[6], W1); bf_f(z[5], z[7], W42);
        bf_f(z[0], z[1], W1); bf_f(z[2], z[3], W1);
        bf_f(z[4], z[5], W1); bf_f(z[6], z[7], W1);
        const float inv = 1.0f / (float)Sv;
        #pragma unroll
        for (int k = 0; k < 8; ++k) {
            const int kk = (int)(__brev((unsigned)(base + k)) >> 21);
            const float m = (kk == 0 || kk == Sv / 2) ? inv : (kk < Sv / 2 ? 2.0f * inv : 0.0f);
            z[k].x *= m; z[k].y *= m;
        }
        bf_i(z[0], z[1], W1); bf_i(z[2], z[3], W1);
        bf_i(z[4], z[5], W1); bf_i(z[6], z[7], W1);
        bf_i(z[0], z[2], W1); bf_i(z[1], z[3], W42);
        bf_i(z[4], z[6], W1); bf_i(z[5], z[7], W42);
        bf_i(z[0], z[4], W1);  bf_i(z[1], z[5], W41);
        bf_i(z[2], z[6], W42); bf_i(z[3], z[7], W43);
        #pragma unroll
        for (int k = 0; k < 8; ++k) zz[base + k] = z[k];
    }
    __syncthreads();

    // ---- inv halves 8,16 (stride 8; two 4-sets) ----
    {
        const int r = t & 7, base0 = (t >> 3) * 32 + r, base1 = base0 + 1024;
        #pragma unroll
        for (int k = 0; k < 4; ++k) { z[k] = zz[base0 + 8 * k]; z[4 + k] = zz[base1 + 8 * k]; }
        bf_i(z[0], z[1], bC1); bf_i(z[2], z[3], bC1);
        bf_i(z[4], z[5], bC1); bf_i(z[6], z[7], bC1);
        const float2 wB = cmi(bC2);
        bf_i(z[0], z[2], bC2); bf_i(z[1], z[3], wB);
        bf_i(z[4], z[6], bC2); bf_i(z[5], z[7], wB);
        #pragma unroll
        for (int k = 0; k < 4; ++k) { zz[base0 + 8 * k] = z[k]; zz[base1 + 8 * k] = z[4 + k]; }
    }
    __syncthreads();

    // ---- inv halves 32,64,128 (stride 32) ----
    {
        const int r = t & 31, base = (t >> 5) * 256 + r;
        #pragma unroll
        for (int k = 0; k < 8; ++k) z[k] = zz[base + 32 * k];
        bf_i(z[0], z[1], bB1); bf_i(z[2], z[3], bB1);
        bf_i(z[4], z[5], bB1); bf_i(z[6], z[7], bB1);
        const float2 wB = cmi(bB2);
        bf_i(z[0], z[2], bB2); bf_i(z[1], z[3], wB);
        bf_i(z[4], z[6], bB2); bf_i(z[5], z[7], wB);
        const float2 w1 = cm1(bB4);
        bf_i(z[0], z[4], bB4);      bf_i(z[1], z[5], w1);
        bf_i(z[2], z[6], cmi(bB4)); bf_i(z[3], z[7], cmi(w1));
        #pragma unroll
        for (int k = 0; k < 8; ++k) zz[base + 32 * k] = z[k];
    }
    __syncthreads();

    // ---- inv halves 256,512,1024 (stride 256) + fused output write ----
    {
        #pragma unroll
        for (int k = 0; k < 8; ++k) z[k] = zz[t + 256 * k];
        bf_i(z[0], z[1], bA1); bf_i(z[2], z[3], bA1);
        bf_i(z[4], z[5], bA1); bf_i(z[6], z[7], bA1);
        const float2 wB = cmi(bA2);
        bf_i(z[0], z[2], bA2); bf_i(z[1], z[3], wB);
        bf_i(z[4], z[6], bA2); bf_i(z[5], z[7], wB);
        const float2 w1 = cm1(bA4);
        bf_i(z[0], z[4], bA4);      bf_i(z[1], z[5], w1);
        bf_i(z[2], z[6], cmi(bA4)); bf_i(z[3], z[7], cmi(w1));
        float* y0 = y + (size_t)c0 * Sv;
        float* y1 = y0 + Sv;
        #pragma unroll
        for (int k = 0; k < 8; ++k) {
            const int n = t + 256 * k;
            y0[n] = z[k].y - x1[n];   // H(x_a) = Im(w) - x_b
            y1[n] = x0[n] - z[k].x;   // H(x_b) = x_a - Re(w)
        }
    }
}

// ---------------------------------------------------------------------------
// Kernel 2: PLI negative-sign partial counts, 8x8 register tiles.
// Grid = B*NSEG; block = 256 = 64 tile positions (8i x 8j) x 4 sample slices.
// Per thread: 8 samples x 8 b128 LDS reads -> 512 cross products (vs 128 reads
// for 512 products in the 4x4 version). Slices are adjacent lanes (t&3) ->
// folded with two __shfl_xor. sign(sin(ti-tj)) == sign(y_i*x_j - x_i*y_j).
// ---------------------------------------------------------------------------
__global__ __launch_bounds__(256) void pli_count_kernel(const float* __restrict__ x,
                                                        const float* __restrict__ y,
                                                        unsigned int* __restrict__ part) {
    __shared__ __align__(16) float xL[SSEG * ROWS];
    __shared__ __align__(16) float yL[SSEG * ROWS];
    const int blk = blockIdx.x;                 // b*NSEG + seg
    const int seg = blk & (NSEG - 1);
    const int b = blk >> 6;
    const int t = threadIdx.x;
    const float* xb = x + (size_t)b * Cv * Sv + seg * SSEG;
    const float* yb = y + (size_t)b * Cv * Sv + seg * SSEG;

    for (int e = t; e < Cv * SSEG; e += 256) {
        const int ch = e >> 5;
        const int s = e & (SSEG - 1);
        xL[s * ROWS + ch] = xb[(size_t)ch * Sv + s];
        yL[s * ROWS + ch] = yb[(size_t)ch * Sv + s];
    }
    __syncthreads();

    const int sl = t & 3;                       // sample slice (adjacent lanes)
    const int tpos = t >> 2;                    // 0..63
    const int ti = tpos >> 3, tj = tpos & 7;
    const int i0 = ti * 8, j0 = tj * 8;
    int neg[8][8] = {};

    #pragma unroll 2
    for (int q = 0; q < 8; ++q) {
        const int s = sl + 4 * q;
        float xi[8], yi[8], xj[8], yj[8];
        *(float4*)&xi[0] = *(const float4*)&xL[s * ROWS + i0];
        *(float4*)&xi[4] = *(const float4*)&xL[s * ROWS + i0 + 4];
        *(float4*)&yi[0] = *(const float4*)&yL[s * ROWS + i0];
        *(float4*)&yi[4] = *(const float4*)&yL[s * ROWS + i0 + 4];
        *(float4*)&xj[0] = *(const float4*)&xL[s * ROWS + j0];
        *(float4*)&xj[4] = *(const float4*)&xL[s * ROWS + j0 + 4];
        *(float4*)&yj[0] = *(const float4*)&yL[s * ROWS + j0];
        *(float4*)&yj[4] = *(const float4*)&yL[s * ROWS + j0 + 4];
        #pragma unroll
        for (int a = 0; a < 8; ++a) {
            #pragma unroll
            for (int c = 0; c < 8; ++c) {
                const float cr = fmaf(yi[a], xj[c], -(xi[a] * yj[c]));
                neg[a][c] += (int)(__float_as_uint(cr) >> 31);
            }
        }
    }

    // fold the 4 sample slices (adjacent lanes)
    #pragma unroll
    for (int a = 0; a < 8; ++a) {
        #pragma unroll
        for (int c = 0; c < 8; ++c) {
            int v = neg[a][c];
            v += __shfl_xor(v, 1);
            v += __shfl_xor(v, 2);
            neg[a][c] = v;
        }
    }

    if (sl == 0) {
        unsigned int* Pb = part + (size_t)blk * (Cv * Cv / 4);   // [64][16] u32
        #pragma unroll
        for (int a = 0; a < 8; ++a) {
            const unsigned int p0 = (unsigned)neg[a][0] | ((unsigned)neg[a][1] << 8)
                                  | ((unsigned)neg[a][2] << 16) | ((unsigned)neg[a][3] << 24);
            const unsigned int p1 = (unsigned)neg[a][4] | ((unsigned)neg[a][5] << 8)
                                  | ((unsigned)neg[a][6] << 16) | ((unsigned)neg[a][7] << 24);
            *(uint2*)&Pb[(i0 + a) * (Cv / 4) + 2 * tj] = make_uint2(p0, p1);
        }
    }
}

// ---------------------------------------------------------------------------
// Kernel 3: unpack + reduce NSEG packed partials -> PLI.
// ---------------------------------------------------------------------------
__global__ __launch_bounds__(256) void finalize_kernel(const unsigned int* __restrict__ part,
                                                       float* __restrict__ out) {
    const int idx = blockIdx.x * 256 + threadIdx.x;   // 65536 = B*C*C
    const int b = idx >> 12;
    const int ij = idx & 4095;
    const int i = ij >> 6, j = ij & 63;
    const unsigned int* p = part + (size_t)b * NSEG * 1024 + i * 16 + (j >> 2);
    const int sh = 8 * (j & 3);
    int negsum = 0;
    #pragma unroll 8
    for (int s = 0; s < NSEG; ++s)
        negsum += (int)((p[s * 1024] >> sh) & 0xFFu);
    out[idx] = (i == j) ? 0.0f
                        : fabsf((float)Sv - 2.0f * (float)negsum) * (1.0f / (float)Sv);
}

extern "C" void kernel_launch(void* const* d_in, const int* in_sizes, int n_in,
                              void* d_out, int out_size, void* d_ws, size_t ws_size,
                              hipStream_t stream) {
    const float* x = (const float*)d_in[0];            // [B, C, S] fp32
    float* y = (float*)d_ws;                           // [B, C, S] fp32 (8 MB)
    unsigned int* part = (unsigned int*)((char*)d_ws + (size_t)Bv * Cv * Sv * sizeof(float));
    float* out = (float*)d_out;                        // [B, C, C] fp32

    hipLaunchKernelGGL(hilbert_kernel, dim3(Bv * Cv / 2), dim3(256), 0, stream, x, y);
    hipLaunchKernelGGL(pli_count_kernel, dim3(Bv * NSEG), dim3(256), 0, stream, x, y, part);
    hipLaunchKernelGGL(finalize_kernel, dim3(Bv * Cv * Cv / 256), dim3(256), 0, stream, part, out);
}

// Round 7
// 84.634 us; speedup vs baseline: 1.1983x; 1.1983x over previous
//
#include <hip/hip_runtime.h>

#define Bv 16
#define Cv 64
#define Sv 2048
#define NSEG 64           // pli segments
#define SSEG 32           // samples per pli segment
#define ROWS 68           // pli LDS row stride in floats (64 ch + 4 pad)

// Forward DIF butterfly: u' = u+v ; v' = (u-v)*w
__device__ __forceinline__ void bf_f(float2& u, float2& v, const float2 w) {
    const float dr = u.x - v.x, di = u.y - v.y;
    u.x += v.x; u.y += v.y;
    v.x = dr * w.x - di * w.y;
    v.y = dr * w.y + di * w.x;
}
// Inverse DIT butterfly: v' = v*conj(w) ; u' = u+v' ; l' = u-v'
__device__ __forceinline__ void bf_i(float2& u, float2& v, const float2 w) {
    const float vr = v.x * w.x + v.y * w.y;
    const float vi = v.y * w.x - v.x * w.y;
    v.x = u.x - vr; v.y = u.y - vi;
    u.x += vr; u.y += vi;
}
__device__ __forceinline__ float2 csq(const float2 a) {
    return make_float2(a.x * a.x - a.y * a.y, 2.0f * a.x * a.y);
}
__device__ __forceinline__ float2 cm1(const float2 a) {   // a * e^{-i pi/4}
    const float cq = 0.70710678118654752f;
    return make_float2(cq * (a.x + a.y), cq * (a.y - a.x));
}
__device__ __forceinline__ float2 cmi(const float2 a) {   // a * e^{-i pi/2}
    return make_float2(a.y, -a.x);
}

// ---------------------------------------------------------------------------
// Kernel 1: paired-channel Hilbert transform, register-grouped FFT with
// register-derived twiddles (no LDS twiddle table).
//   z = x_a + i*x_b ; w = ifft(h .* fft(z)) ; H(x_a)=Im(w)-x_b ; H(x_b)=x_a-Re(w)
// Twiddle identity: w(half, pos) = exp(-i*pi*pos/half); for a stage group with
// pos = r + 32k (or r + 256k): w = base(r) * e^{-i*pi*k/4}; next half uses
// base^2. One block per channel pair (512 blocks).
// ---------------------------------------------------------------------------
__global__ __launch_bounds__(256) void hilbert_kernel(const float* __restrict__ x,
                                                      float* __restrict__ y) {
    __shared__ float2 zz[Sv];     // 16 KB
    const int t = threadIdx.x;
    const int c0 = blockIdx.x * 2;
    const float* x0 = x + (size_t)c0 * Sv;
    const float* x1 = x0 + Sv;

    const float PI = 3.14159265358979323846f;
    float2 bA4, bB4, bC2;
    sincosf(-PI * (float)t * (1.0f / 1024.0f), &bA4.y, &bA4.x);        // exp(-i pi t/1024)
    sincosf(-PI * (float)(t & 31) * (1.0f / 128.0f), &bB4.y, &bB4.x);  // exp(-i pi r/128)
    sincosf(-PI * (float)(t & 7) * (1.0f / 16.0f), &bC2.y, &bC2.x);    // exp(-i pi r/16)
    const float2 bA2 = csq(bA4), bA1 = csq(bA2);
    const float2 bB2 = csq(bB4), bB1 = csq(bB2);
    const float2 bC1 = csq(bC2);

    float2 z[8];
    #pragma unroll
    for (int k = 0; k < 8; ++k)
        z[k] = make_float2(x0[t + 256 * k], x1[t + 256 * k]);

    // ---- fwd halves 1024,512,256 (stride 256; n_k = t + 256k) ----
    {
        const float2 w1 = cm1(bA4);
        bf_f(z[0], z[4], bA4);      bf_f(z[1], z[5], w1);
        bf_f(z[2], z[6], cmi(bA4)); bf_f(z[3], z[7], cmi(w1));
        const float2 wB = cmi(bA2);
        bf_f(z[0], z[2], bA2); bf_f(z[1], z[3], wB);
        bf_f(z[4], z[6], bA2); bf_f(z[5], z[7], wB);
        bf_f(z[0], z[1], bA1); bf_f(z[2], z[3], bA1);
        bf_f(z[4], z[5], bA1); bf_f(z[6], z[7], bA1);
    }
    #pragma unroll
    for (int k = 0; k < 8; ++k) zz[t + 256 * k] = z[k];
    __syncthreads();

    // ---- fwd halves 128,64,32 (stride 32) ----
    {
        const int r = t & 31, base = (t >> 5) * 256 + r;
        #pragma unroll
        for (int k = 0; k < 8; ++k) z[k] = zz[base + 32 * k];
        const float2 w1 = cm1(bB4);
        bf_f(z[0], z[4], bB4);      bf_f(z[1], z[5], w1);
        bf_f(z[2], z[6], cmi(bB4)); bf_f(z[3], z[7], cmi(w1));
        const float2 wB = cmi(bB2);
        bf_f(z[0], z[2], bB2); bf_f(z[1], z[3], wB);
        bf_f(z[4], z[6], bB2); bf_f(z[5], z[7], wB);
        bf_f(z[0], z[1], bB1); bf_f(z[2], z[3], bB1);
        bf_f(z[4], z[5], bB1); bf_f(z[6], z[7], bB1);
        #pragma unroll
        for (int k = 0; k < 8; ++k) zz[base + 32 * k] = z[k];
    }
    __syncthreads();

    // ---- fwd halves 16,8 (stride 8; two 4-sets) ----
    {
        const int r = t & 7, base0 = (t >> 3) * 32 + r, base1 = base0 + 1024;
        #pragma unroll
        for (int k = 0; k < 4; ++k) { z[k] = zz[base0 + 8 * k]; z[4 + k] = zz[base1 + 8 * k]; }
        const float2 wB = cmi(bC2);
        bf_f(z[0], z[2], bC2); bf_f(z[1], z[3], wB);
        bf_f(z[4], z[6], bC2); bf_f(z[5], z[7], wB);
        bf_f(z[0], z[1], bC1); bf_f(z[2], z[3], bC1);
        bf_f(z[4], z[5], bC1); bf_f(z[6], z[7], bC1);
        #pragma unroll
        for (int k = 0; k < 4; ++k) { zz[base0 + 8 * k] = z[k]; zz[base1 + 8 * k] = z[4 + k]; }
    }
    __syncthreads();

    // ---- fused: fwd 4,2,1 ; Hilbert filter * 1/N ; inv 1,2,4 ----
    {
        const int base = 8 * t;
        #pragma unroll
        for (int k = 0; k < 8; ++k) z[k] = zz[base + k];
        const float cq = 0.70710678118654752f;
        const float2 W1  = make_float2(1.0f, 0.0f);
        const float2 W41 = make_float2(cq, -cq);
        const float2 W42 = make_float2(0.0f, -1.0f);
        const float2 W43 = make_float2(-cq, -cq);
        bf_f(z[0], z[4], W1);  bf_f(z[1], z[5], W41);
        bf_f(z[2], z[6], W42); bf_f(z[3], z[7], W43);
        bf_f(z[0], z[2], W1); bf_f(z[1], z[3], W42);
        bf_f(z[4], z[6], W1); bf_f(z[5], z[7], W42);
        bf_f(z[0], z[1], W1); bf_f(z[2], z[3], W1);
        bf_f(z[4], z[5], W1); bf_f(z[6], z[7], W1);
        const float inv = 1.0f / (float)Sv;
        #pragma unroll
        for (int k = 0; k < 8; ++k) {
            const int kk = (int)(__brev((unsigned)(base + k)) >> 21);
            const float m = (kk == 0 || kk == Sv / 2) ? inv : (kk < Sv / 2 ? 2.0f * inv : 0.0f);
            z[k].x *= m; z[k].y *= m;
        }
        bf_i(z[0], z[1], W1); bf_i(z[2], z[3], W1);
        bf_i(z[4], z[5], W1); bf_i(z[6], z[7], W1);
        bf_i(z[0], z[2], W1); bf_i(z[1], z[3], W42);
        bf_i(z[4], z[6], W1); bf_i(z[5], z[7], W42);
        bf_i(z[0], z[4], W1);  bf_i(z[1], z[5], W41);
        bf_i(z[2], z[6], W42); bf_i(z[3], z[7], W43);
        #pragma unroll
        for (int k = 0; k < 8; ++k) zz[base + k] = z[k];
    }
    __syncthreads();

    // ---- inv halves 8,16 (stride 8; two 4-sets) ----
    {
        const int r = t & 7, base0 = (t >> 3) * 32 + r, base1 = base0 + 1024;
        #pragma unroll
        for (int k = 0; k < 4; ++k) { z[k] = zz[base0 + 8 * k]; z[4 + k] = zz[base1 + 8 * k]; }
        bf_i(z[0], z[1], bC1); bf_i(z[2], z[3], bC1);
        bf_i(z[4], z[5], bC1); bf_i(z[6], z[7], bC1);
        const float2 wB = cmi(bC2);
        bf_i(z[0], z[2], bC2); bf_i(z[1], z[3], wB);
        bf_i(z[4], z[6], bC2); bf_i(z[5], z[7], wB);
        #pragma unroll
        for (int k = 0; k < 4; ++k) { zz[base0 + 8 * k] = z[k]; zz[base1 + 8 * k] = z[4 + k]; }
    }
    __syncthreads();

    // ---- inv halves 32,64,128 (stride 32) ----
    {
        const int r = t & 31, base = (t >> 5) * 256 + r;
        #pragma unroll
        for (int k = 0; k < 8; ++k) z[k] = zz[base + 32 * k];
        bf_i(z[0], z[1], bB1); bf_i(z[2], z[3], bB1);
        bf_i(z[4], z[5], bB1); bf_i(z[6], z[7], bB1);
        const float2 wB = cmi(bB2);
        bf_i(z[0], z[2], bB2); bf_i(z[1], z[3], wB);
        bf_i(z[4], z[6], bB2); bf_i(z[5], z[7], wB);
        const float2 w1 = cm1(bB4);
        bf_i(z[0], z[4], bB4);      bf_i(z[1], z[5], w1);
        bf_i(z[2], z[6], cmi(bB4)); bf_i(z[3], z[7], cmi(w1));
        #pragma unroll
        for (int k = 0; k < 8; ++k) zz[base + 32 * k] = z[k];
    }
    __syncthreads();

    // ---- inv halves 256,512,1024 (stride 256) + fused output write ----
    {
        #pragma unroll
        for (int k = 0; k < 8; ++k) z[k] = zz[t + 256 * k];
        bf_i(z[0], z[1], bA1); bf_i(z[2], z[3], bA1);
        bf_i(z[4], z[5], bA1); bf_i(z[6], z[7], bA1);
        const float2 wB = cmi(bA2);
        bf_i(z[0], z[2], bA2); bf_i(z[1], z[3], wB);
        bf_i(z[4], z[6], bA2); bf_i(z[5], z[7], wB);
        const float2 w1 = cm1(bA4);
        bf_i(z[0], z[4], bA4);      bf_i(z[1], z[5], w1);
        bf_i(z[2], z[6], cmi(bA4)); bf_i(z[3], z[7], cmi(w1));
        float* y0 = y + (size_t)c0 * Sv;
        float* y1 = y0 + Sv;
        #pragma unroll
        for (int k = 0; k < 8; ++k) {
            const int n = t + 256 * k;
            y0[n] = z[k].y - x1[n];   // H(x_a) = Im(w) - x_b
            y1[n] = x0[n] - z[k].x;   // H(x_b) = x_a - Re(w)
        }
    }
}

// ---------------------------------------------------------------------------
// Kernel 2: PLI negative-sign partial counts (R4-proven 4x4 version).
// Grid = B * NSEG; block = 256 = 16x16 threads, each computing a 4x4 pair
// tile over 32 samples. sign(sin(ti-tj)) == sign(y_i*x_j - x_i*y_j).
// Partials packed 4 x u8 per u32 (per-segment count <= 32 fits a byte).
// ---------------------------------------------------------------------------
__global__ __launch_bounds__(256) void pli_count_kernel(const float* __restrict__ x,
                                                        const float* __restrict__ y,
                                                        unsigned int* __restrict__ part) {
    __shared__ __align__(16) float xL[SSEG * ROWS];
    __shared__ __align__(16) float yL[SSEG * ROWS];
    const int blk = blockIdx.x;                 // b*NSEG + seg
    const int seg = blk & (NSEG - 1);
    const int b = blk >> 6;
    const int t = threadIdx.x;
    const float* xb = x + (size_t)b * Cv * Sv + seg * SSEG;
    const float* yb = y + (size_t)b * Cv * Sv + seg * SSEG;

    for (int e = t; e < Cv * SSEG; e += 256) {
        const int ch = e >> 5;
        const int s = e & (SSEG - 1);
        xL[s * ROWS + ch] = xb[(size_t)ch * Sv + s];
        yL[s * ROWS + ch] = yb[(size_t)ch * Sv + s];
    }
    __syncthreads();

    const int ti = t >> 4, tj = t & 15;
    const int i0 = ti * 4, j0 = tj * 4;
    int neg[4][4] = {};

    #pragma unroll 4
    for (int s = 0; s < SSEG; ++s) {
        const float4 xi = *(const float4*)&xL[s * ROWS + i0];
        const float4 yi = *(const float4*)&yL[s * ROWS + i0];
        const float4 xj = *(const float4*)&xL[s * ROWS + j0];
        const float4 yj = *(const float4*)&yL[s * ROWS + j0];
        const float xia[4] = {xi.x, xi.y, xi.z, xi.w};
        const float yia[4] = {yi.x, yi.y, yi.z, yi.w};
        const float xja[4] = {xj.x, xj.y, xj.z, xj.w};
        const float yja[4] = {yj.x, yj.y, yj.z, yj.w};
        #pragma unroll
        for (int a = 0; a < 4; ++a) {
            #pragma unroll
            for (int c = 0; c < 4; ++c) {
                const float cr = fmaf(yia[a], xja[c], -(xia[a] * yja[c]));
                neg[a][c] += (int)(__float_as_uint(cr) >> 31);
            }
        }
    }

    unsigned int* Pb = part + (size_t)(b * NSEG + seg) * (Cv * Cv / 4);  // [64][16] u32
    #pragma unroll
    for (int a = 0; a < 4; ++a) {
        const unsigned int p = (unsigned)neg[a][0] | ((unsigned)neg[a][1] << 8)
                             | ((unsigned)neg[a][2] << 16) | ((unsigned)neg[a][3] << 24);
        Pb[(i0 + a) * (Cv / 4) + tj] = p;
    }
}

// ---------------------------------------------------------------------------
// Kernel 3: unpack + reduce NSEG packed partials -> PLI.
// ---------------------------------------------------------------------------
__global__ __launch_bounds__(256) void finalize_kernel(const unsigned int* __restrict__ part,
                                                       float* __restrict__ out) {
    const int idx = blockIdx.x * 256 + threadIdx.x;   // 65536 = B*C*C
    const int b = idx >> 12;
    const int ij = idx & 4095;
    const int i = ij >> 6, j = ij & 63;
    const unsigned int* p = part + (size_t)b * NSEG * 1024 + i * 16 + (j >> 2);
    const int sh = 8 * (j & 3);
    int negsum = 0;
    #pragma unroll 8
    for (int s = 0; s < NSEG; ++s)
        negsum += (int)((p[s * 1024] >> sh) & 0xFFu);
    out[idx] = (i == j) ? 0.0f
                        : fabsf((float)Sv - 2.0f * (float)negsum) * (1.0f / (float)Sv);
}

extern "C" void kernel_launch(void* const* d_in, const int* in_sizes, int n_in,
                              void* d_out, int out_size, void* d_ws, size_t ws_size,
                              hipStream_t stream) {
    const float* x = (const float*)d_in[0];            // [B, C, S] fp32
    float* y = (float*)d_ws;                           // [B, C, S] fp32 (8 MB)
    unsigned int* part = (unsigned int*)((char*)d_ws + (size_t)Bv * Cv * Sv * sizeof(float));
    float* out = (float*)d_out;                        // [B, C, C] fp32

    hipLaunchKernelGGL(hilbert_kernel, dim3(Bv * Cv / 2), dim3(256), 0, stream, x, y);
    hipLaunchKernelGGL(pli_count_kernel, dim3(Bv * NSEG), dim3(256), 0, stream, x, y, part);
    hipLaunchKernelGGL(finalize_kernel, dim3(Bv * Cv * Cv / 256), dim3(256), 0, stream, part, out);
}

// Round 8
// 82.252 us; speedup vs baseline: 1.2330x; 1.0290x over previous
//
#include <hip/hip_runtime.h>

#define Bv 16
#define Cv 64
#define Sv 2048
#define NSEG 64           // pli segments
#define SSEG 32           // samples per pli segment
#define ROWS 68           // pli LDS row stride in floats (64 ch + 4 pad)
#define NTILE 144         // triangle tiles: dq in 0..8 x qi in 0..15

// Forward DIF butterfly: u' = u+v ; v' = (u-v)*w
__device__ __forceinline__ void bf_f(float2& u, float2& v, const float2 w) {
    const float dr = u.x - v.x, di = u.y - v.y;
    u.x += v.x; u.y += v.y;
    v.x = dr * w.x - di * w.y;
    v.y = dr * w.y + di * w.x;
}
// Inverse DIT butterfly: v' = v*conj(w) ; u' = u+v' ; l' = u-v'
__device__ __forceinline__ void bf_i(float2& u, float2& v, const float2 w) {
    const float vr = v.x * w.x + v.y * w.y;
    const float vi = v.y * w.x - v.x * w.y;
    v.x = u.x - vr; v.y = u.y - vi;
    u.x += vr; u.y += vi;
}
__device__ __forceinline__ float2 csq(const float2 a) {
    return make_float2(a.x * a.x - a.y * a.y, 2.0f * a.x * a.y);
}
__device__ __forceinline__ float2 cm1(const float2 a) {   // a * e^{-i pi/4}
    const float cq = 0.70710678118654752f;
    return make_float2(cq * (a.x + a.y), cq * (a.y - a.x));
}
__device__ __forceinline__ float2 cmi(const float2 a) {   // a * e^{-i pi/2}
    return make_float2(a.y, -a.x);
}

// ---------------------------------------------------------------------------
// Kernel 1: paired-channel Hilbert transform (byte-identical to R7).
// ---------------------------------------------------------------------------
__global__ __launch_bounds__(256) void hilbert_kernel(const float* __restrict__ x,
                                                      float* __restrict__ y) {
    __shared__ float2 zz[Sv];     // 16 KB
    const int t = threadIdx.x;
    const int c0 = blockIdx.x * 2;
    const float* x0 = x + (size_t)c0 * Sv;
    const float* x1 = x0 + Sv;

    const float PI = 3.14159265358979323846f;
    float2 bA4, bB4, bC2;
    sincosf(-PI * (float)t * (1.0f / 1024.0f), &bA4.y, &bA4.x);
    sincosf(-PI * (float)(t & 31) * (1.0f / 128.0f), &bB4.y, &bB4.x);
    sincosf(-PI * (float)(t & 7) * (1.0f / 16.0f), &bC2.y, &bC2.x);
    const float2 bA2 = csq(bA4), bA1 = csq(bA2);
    const float2 bB2 = csq(bB4), bB1 = csq(bB2);
    const float2 bC1 = csq(bC2);

    float2 z[8];
    #pragma unroll
    for (int k = 0; k < 8; ++k)
        z[k] = make_float2(x0[t + 256 * k], x1[t + 256 * k]);

    // ---- fwd halves 1024,512,256 (stride 256) ----
    {
        const float2 w1 = cm1(bA4);
        bf_f(z[0], z[4], bA4);      bf_f(z[1], z[5], w1);
        bf_f(z[2], z[6], cmi(bA4)); bf_f(z[3], z[7], cmi(w1));
        const float2 wB = cmi(bA2);
        bf_f(z[0], z[2], bA2); bf_f(z[1], z[3], wB);
        bf_f(z[4], z[6], bA2); bf_f(z[5], z[7], wB);
        bf_f(z[0], z[1], bA1); bf_f(z[2], z[3], bA1);
        bf_f(z[4], z[5], bA1); bf_f(z[6], z[7], bA1);
    }
    #pragma unroll
    for (int k = 0; k < 8; ++k) zz[t + 256 * k] = z[k];
    __syncthreads();

    // ---- fwd halves 128,64,32 (stride 32) ----
    {
        const int r = t & 31, base = (t >> 5) * 256 + r;
        #pragma unroll
        for (int k = 0; k < 8; ++k) z[k] = zz[base + 32 * k];
        const float2 w1 = cm1(bB4);
        bf_f(z[0], z[4], bB4);      bf_f(z[1], z[5], w1);
        bf_f(z[2], z[6], cmi(bB4)); bf_f(z[3], z[7], cmi(w1));
        const float2 wB = cmi(bB2);
        bf_f(z[0], z[2], bB2); bf_f(z[1], z[3], wB);
        bf_f(z[4], z[6], bB2); bf_f(z[5], z[7], wB);
        bf_f(z[0], z[1], bB1); bf_f(z[2], z[3], bB1);
        bf_f(z[4], z[5], bB1); bf_f(z[6], z[7], bB1);
        #pragma unroll
        for (int k = 0; k < 8; ++k) zz[base + 32 * k] = z[k];
    }
    __syncthreads();

    // ---- fwd halves 16,8 (stride 8; two 4-sets) ----
    {
        const int r = t & 7, base0 = (t >> 3) * 32 + r, base1 = base0 + 1024;
        #pragma unroll
        for (int k = 0; k < 4; ++k) { z[k] = zz[base0 + 8 * k]; z[4 + k] = zz[base1 + 8 * k]; }
        const float2 wB = cmi(bC2);
        bf_f(z[0], z[2], bC2); bf_f(z[1], z[3], wB);
        bf_f(z[4], z[6], bC2); bf_f(z[5], z[7], wB);
        bf_f(z[0], z[1], bC1); bf_f(z[2], z[3], bC1);
        bf_f(z[4], z[5], bC1); bf_f(z[6], z[7], bC1);
        #pragma unroll
        for (int k = 0; k < 4; ++k) { zz[base0 + 8 * k] = z[k]; zz[base1 + 8 * k] = z[4 + k]; }
    }
    __syncthreads();

    // ---- fused: fwd 4,2,1 ; Hilbert filter * 1/N ; inv 1,2,4 ----
    {
        const int base = 8 * t;
        #pragma unroll
        for (int k = 0; k < 8; ++k) z[k] = zz[base + k];
        const float cq = 0.70710678118654752f;
        const float2 W1  = make_float2(1.0f, 0.0f);
        const float2 W41 = make_float2(cq, -cq);
        const float2 W42 = make_float2(0.0f, -1.0f);
        const float2 W43 = make_float2(-cq, -cq);
        bf_f(z[0], z[4], W1);  bf_f(z[1], z[5], W41);
        bf_f(z[2], z[6], W42); bf_f(z[3], z[7], W43);
        bf_f(z[0], z[2], W1); bf_f(z[1], z[3], W42);
        bf_f(z[4], z[6], W1); bf_f(z[5], z[7], W42);
        bf_f(z[0], z[1], W1); bf_f(z[2], z[3], W1);
        bf_f(z[4], z[5], W1); bf_f(z[6], z[7], W1);
        const float inv = 1.0f / (float)Sv;
        #pragma unroll
        for (int k = 0; k < 8; ++k) {
            const int kk = (int)(__brev((unsigned)(base + k)) >> 21);
            const float m = (kk == 0 || kk == Sv / 2) ? inv : (kk < Sv / 2 ? 2.0f * inv : 0.0f);
            z[k].x *= m; z[k].y *= m;
        }
        bf_i(z[0], z[1], W1); bf_i(z[2], z[3], W1);
        bf_i(z[4], z[5], W1); bf_i(z[6], z[7], W1);
        bf_i(z[0], z[2], W1); bf_i(z[1], z[3], W42);
        bf_i(z[4], z[6], W1); bf_i(z[5], z[7], W42);
        bf_i(z[0], z[4], W1);  bf_i(z[1], z[5], W41);
        bf_i(z[2], z[6], W42); bf_i(z[3], z[7], W43);
        #pragma unroll
        for (int k = 0; k < 8; ++k) zz[base + k] = z[k];
    }
    __syncthreads();

    // ---- inv halves 8,16 (stride 8; two 4-sets) ----
    {
        const int r = t & 7, base0 = (t >> 3) * 32 + r, base1 = base0 + 1024;
        #pragma unroll
        for (int k = 0; k < 4; ++k) { z[k] = zz[base0 + 8 * k]; z[4 + k] = zz[base1 + 8 * k]; }
        bf_i(z[0], z[1], bC1); bf_i(z[2], z[3], bC1);
        bf_i(z[4], z[5], bC1); bf_i(z[6], z[7], bC1);
        const float2 wB = cmi(bC2);
        bf_i(z[0], z[2], bC2); bf_i(z[1], z[3], wB);
        bf_i(z[4], z[6], bC2); bf_i(z[5], z[7], wB);
        #pragma unroll
        for (int k = 0; k < 4; ++k) { zz[base0 + 8 * k] = z[k]; zz[base1 + 8 * k] = z[4 + k]; }
    }
    __syncthreads();

    // ---- inv halves 32,64,128 (stride 32) ----
    {
        const int r = t & 31, base = (t >> 5) * 256 + r;
        #pragma unroll
        for (int k = 0; k < 8; ++k) z[k] = zz[base + 32 * k];
        bf_i(z[0], z[1], bB1); bf_i(z[2], z[3], bB1);
        bf_i(z[4], z[5], bB1); bf_i(z[6], z[7], bB1);
        const float2 wB = cmi(bB2);
        bf_i(z[0], z[2], bB2); bf_i(z[1], z[3], wB);
        bf_i(z[4], z[6], bB2); bf_i(z[5], z[7], wB);
        const float2 w1 = cm1(bB4);
        bf_i(z[0], z[4], bB4);      bf_i(z[1], z[5], w1);
        bf_i(z[2], z[6], cmi(bB4)); bf_i(z[3], z[7], cmi(w1));
        #pragma unroll
        for (int k = 0; k < 8; ++k) zz[base + 32 * k] = z[k];
    }
    __syncthreads();

    // ---- inv halves 256,512,1024 (stride 256) + fused output write ----
    {
        #pragma unroll
        for (int k = 0; k < 8; ++k) z[k] = zz[t + 256 * k];
        bf_i(z[0], z[1], bA1); bf_i(z[2], z[3], bA1);
        bf_i(z[4], z[5], bA1); bf_i(z[6], z[7], bA1);
        const float2 wB = cmi(bA2);
        bf_i(z[0], z[2], bA2); bf_i(z[1], z[3], wB);
        bf_i(z[4], z[6], bA2); bf_i(z[5], z[7], wB);
        const float2 w1 = cm1(bA4);
        bf_i(z[0], z[4], bA4);      bf_i(z[1], z[5], w1);
        bf_i(z[2], z[6], cmi(bA4)); bf_i(z[3], z[7], cmi(w1));
        float* y0 = y + (size_t)c0 * Sv;
        float* y1 = y0 + Sv;
        #pragma unroll
        for (int k = 0; k < 8; ++k) {
            const int n = t + 256 * k;
            y0[n] = z[k].y - x1[n];   // H(x_a) = Im(w) - x_b
            y1[n] = x0[n] - z[k].x;   // H(x_b) = x_a - Re(w)
        }
    }
}

// ---------------------------------------------------------------------------
// Kernel 2: PLI negative-sign partial counts, TRIANGLE tiling.
// Antisymmetry: sign(sin(tj-ti)) = -sign(sin(ti-tj)) => neg(j,i) = S - neg(i,j)
// and |S-2n| is invariant under n -> S-n, so only ordered tiles with quad-diff
// dq in 0..8 are computed. Job t = dq*16+qi (t < 144): 4x4 outer-product tile
// (i-quad qi, j-quad (qi+dq) mod 16) over 32 samples. dq=8 tiles are computed
// from both sides (finalize uses whichever matches its orientation); dq=0
// tiles include diagonal junk (finalize forces 0). Threads 144..255 idle in
// compute (staging uses all 256).
// ---------------------------------------------------------------------------
__global__ __launch_bounds__(256) void pli_count_kernel(const float* __restrict__ x,
                                                        const float* __restrict__ y,
                                                        unsigned int* __restrict__ part) {
    __shared__ __align__(16) float xL[SSEG * ROWS];
    __shared__ __align__(16) float yL[SSEG * ROWS];
    const int blk = blockIdx.x;                 // b*NSEG + seg
    const int seg = blk & (NSEG - 1);
    const int b = blk >> 6;
    const int t = threadIdx.x;
    const float* xb = x + (size_t)b * Cv * Sv + seg * SSEG;
    const float* yb = y + (size_t)b * Cv * Sv + seg * SSEG;

    for (int e = t; e < Cv * SSEG; e += 256) {
        const int ch = e >> 5;
        const int s = e & (SSEG - 1);
        xL[s * ROWS + ch] = xb[(size_t)ch * Sv + s];
        yL[s * ROWS + ch] = yb[(size_t)ch * Sv + s];
    }
    __syncthreads();

    if (t < NTILE) {
        const int qi = t & 15;
        const int dq = t >> 4;                  // 0..8
        const int i0 = qi * 4;
        const int j0 = ((qi + dq) & 15) * 4;
        int neg[4][4] = {};

        #pragma unroll 4
        for (int s = 0; s < SSEG; ++s) {
            const float4 xi = *(const float4*)&xL[s * ROWS + i0];
            const float4 yi = *(const float4*)&yL[s * ROWS + i0];
            const float4 xj = *(const float4*)&xL[s * ROWS + j0];
            const float4 yj = *(const float4*)&yL[s * ROWS + j0];
            const float xia[4] = {xi.x, xi.y, xi.z, xi.w};
            const float yia[4] = {yi.x, yi.y, yi.z, yi.w};
            const float xja[4] = {xj.x, xj.y, xj.z, xj.w};
            const float yja[4] = {yj.x, yj.y, yj.z, yj.w};
            #pragma unroll
            for (int a = 0; a < 4; ++a) {
                #pragma unroll
                for (int c = 0; c < 4; ++c) {
                    const float cr = fmaf(yia[a], xja[c], -(xia[a] * yja[c]));
                    neg[a][c] += (int)(__float_as_uint(cr) >> 31);
                }
            }
        }

        // part[gseg][tile][a][c] as u8, packed 4 per u32, 16 B per tile
        unsigned int* Pb = part + ((size_t)blk * NTILE + t) * 4;
        unsigned int pk[4];
        #pragma unroll
        for (int a = 0; a < 4; ++a)
            pk[a] = (unsigned)neg[a][0] | ((unsigned)neg[a][1] << 8)
                  | ((unsigned)neg[a][2] << 16) | ((unsigned)neg[a][3] << 24);
        *(uint4*)Pb = make_uint4(pk[0], pk[1], pk[2], pk[3]);
    }
}

// ---------------------------------------------------------------------------
// Kernel 3: reduce triangle partials -> PLI.
// For output (i,j): g=(qj-qi)&15. g<=8: n = P[g*16+qi][a*4+c] (direct);
// g>8: n' = P[(16-g)*16+qj][c*4+a] = neg(j,i); |S-2n'| == |S-2(S-n')| so the
// same formula applies. Diagonal forced to 0.
// ---------------------------------------------------------------------------
__global__ __launch_bounds__(256) void finalize_kernel(const unsigned char* __restrict__ part,
                                                       float* __restrict__ out) {
    const int idx = blockIdx.x * 256 + threadIdx.x;   // 65536 = B*C*C
    const int b = idx >> 12;
    const int ij = idx & 4095;
    const int i = ij >> 6, j = ij & 63;
    const int qi = i >> 2, a = i & 3;
    const int qj = j >> 2, c = j & 3;
    const int g = (qj - qi) & 15;
    int byteoff;
    if (g <= 8) byteoff = (g * 16 + qi) * 16 + a * 4 + c;
    else        byteoff = ((16 - g) * 16 + qj) * 16 + c * 4 + a;
    const unsigned char* p = part + (size_t)b * NSEG * (NTILE * 16) + byteoff;
    int negsum = 0;
    #pragma unroll 8
    for (int s = 0; s < NSEG; ++s)
        negsum += (int)p[s * (NTILE * 16)];
    out[idx] = (i == j) ? 0.0f
                        : fabsf((float)Sv - 2.0f * (float)negsum) * (1.0f / (float)Sv);
}

extern "C" void kernel_launch(void* const* d_in, const int* in_sizes, int n_in,
                              void* d_out, int out_size, void* d_ws, size_t ws_size,
                              hipStream_t stream) {
    const float* x = (const float*)d_in[0];            // [B, C, S] fp32
    float* y = (float*)d_ws;                           // [B, C, S] fp32 (8 MB)
    unsigned int* part = (unsigned int*)((char*)d_ws + (size_t)Bv * Cv * Sv * sizeof(float));
    float* out = (float*)d_out;                        // [B, C, C] fp32

    hipLaunchKernelGGL(hilbert_kernel, dim3(Bv * Cv / 2), dim3(256), 0, stream, x, y);
    hipLaunchKernelGGL(pli_count_kernel, dim3(Bv * NSEG), dim3(256), 0, stream, x, y, part);
    hipLaunchKernelGGL(finalize_kernel, dim3(Bv * Cv * Cv / 256), dim3(256), 0, stream,
                       (const unsigned char*)part, out);
}

// Round 9
// 81.712 us; speedup vs baseline: 1.2412x; 1.0066x over previous
//
#include <hip/hip_runtime.h>

#define Bv 16
#define Cv 64
#define Sv 2048
#define NSEG 64           // pli segments
#define SSEG 32           // samples per pli segment
#define ROWS 68           // pli LDS row stride in floats (64 ch + 4 pad)
#define NTILE 144         // triangle tiles: dq in 0..8 x qi in 0..15

// Forward DIF butterfly: u' = u+v ; v' = (u-v)*w
__device__ __forceinline__ void bf_f(float2& u, float2& v, const float2 w) {
    const float dr = u.x - v.x, di = u.y - v.y;
    u.x += v.x; u.y += v.y;
    v.x = dr * w.x - di * w.y;
    v.y = dr * w.y + di * w.x;
}
// Inverse DIT butterfly: v' = v*conj(w) ; u' = u+v' ; l' = u-v'
__device__ __forceinline__ void bf_i(float2& u, float2& v, const float2 w) {
    const float vr = v.x * w.x + v.y * w.y;
    const float vi = v.y * w.x - v.x * w.y;
    v.x = u.x - vr; v.y = u.y - vi;
    u.x += vr; u.y += vi;
}
__device__ __forceinline__ float2 csq(const float2 a) {
    return make_float2(a.x * a.x - a.y * a.y, 2.0f * a.x * a.y);
}
__device__ __forceinline__ float2 cm1(const float2 a) {   // a * e^{-i pi/4}
    const float cq = 0.70710678118654752f;
    return make_float2(cq * (a.x + a.y), cq * (a.y - a.x));
}
__device__ __forceinline__ float2 cmi(const float2 a) {   // a * e^{-i pi/2}
    return make_float2(a.y, -a.x);
}
// Bank-conflict-breaking storage map for the FFT scratch: n -> n + n/8.
// Unpadded, the fused round (zz[8t+k]) hits banks {0,16} (32-way, ~11x per
// m136) and the stride-8 rounds are 8-way. Padded: all rounds <= ~2-way.
__device__ __forceinline__ int pad(int n) { return n + (n >> 3); }

// ---------------------------------------------------------------------------
// Kernel 1: paired-channel Hilbert transform (R7 logic + padded LDS map).
// ---------------------------------------------------------------------------
__global__ __launch_bounds__(256) void hilbert_kernel(const float* __restrict__ x,
                                                      float* __restrict__ y) {
    __shared__ float2 zz[Sv + Sv / 8];   // 2304 float2 = 18 KB (padded map)
    const int t = threadIdx.x;
    const int c0 = blockIdx.x * 2;
    const float* x0 = x + (size_t)c0 * Sv;
    const float* x1 = x0 + Sv;

    const float PI = 3.14159265358979323846f;
    float2 bA4, bB4, bC2;
    sincosf(-PI * (float)t * (1.0f / 1024.0f), &bA4.y, &bA4.x);
    sincosf(-PI * (float)(t & 31) * (1.0f / 128.0f), &bB4.y, &bB4.x);
    sincosf(-PI * (float)(t & 7) * (1.0f / 16.0f), &bC2.y, &bC2.x);
    const float2 bA2 = csq(bA4), bA1 = csq(bA2);
    const float2 bB2 = csq(bB4), bB1 = csq(bB2);
    const float2 bC1 = csq(bC2);

    float2 z[8];
    #pragma unroll
    for (int k = 0; k < 8; ++k)
        z[k] = make_float2(x0[t + 256 * k], x1[t + 256 * k]);

    // ---- fwd halves 1024,512,256 (stride 256) ----
    {
        const float2 w1 = cm1(bA4);
        bf_f(z[0], z[4], bA4);      bf_f(z[1], z[5], w1);
        bf_f(z[2], z[6], cmi(bA4)); bf_f(z[3], z[7], cmi(w1));
        const float2 wB = cmi(bA2);
        bf_f(z[0], z[2], bA2); bf_f(z[1], z[3], wB);
        bf_f(z[4], z[6], bA2); bf_f(z[5], z[7], wB);
        bf_f(z[0], z[1], bA1); bf_f(z[2], z[3], bA1);
        bf_f(z[4], z[5], bA1); bf_f(z[6], z[7], bA1);
    }
    #pragma unroll
    for (int k = 0; k < 8; ++k) zz[pad(t + 256 * k)] = z[k];
    __syncthreads();

    // ---- fwd halves 128,64,32 (stride 32) ----
    {
        const int r = t & 31, base = (t >> 5) * 256 + r;
        #pragma unroll
        for (int k = 0; k < 8; ++k) z[k] = zz[pad(base + 32 * k)];
        const float2 w1 = cm1(bB4);
        bf_f(z[0], z[4], bB4);      bf_f(z[1], z[5], w1);
        bf_f(z[2], z[6], cmi(bB4)); bf_f(z[3], z[7], cmi(w1));
        const float2 wB = cmi(bB2);
        bf_f(z[0], z[2], bB2); bf_f(z[1], z[3], wB);
        bf_f(z[4], z[6], bB2); bf_f(z[5], z[7], wB);
        bf_f(z[0], z[1], bB1); bf_f(z[2], z[3], bB1);
        bf_f(z[4], z[5], bB1); bf_f(z[6], z[7], bB1);
        #pragma unroll
        for (int k = 0; k < 8; ++k) zz[pad(base + 32 * k)] = z[k];
    }
    __syncthreads();

    // ---- fwd halves 16,8 (stride 8; two 4-sets) ----
    {
        const int r = t & 7, base0 = (t >> 3) * 32 + r, base1 = base0 + 1024;
        #pragma unroll
        for (int k = 0; k < 4; ++k) {
            z[k] = zz[pad(base0 + 8 * k)];
            z[4 + k] = zz[pad(base1 + 8 * k)];
        }
        const float2 wB = cmi(bC2);
        bf_f(z[0], z[2], bC2); bf_f(z[1], z[3], wB);
        bf_f(z[4], z[6], bC2); bf_f(z[5], z[7], wB);
        bf_f(z[0], z[1], bC1); bf_f(z[2], z[3], bC1);
        bf_f(z[4], z[5], bC1); bf_f(z[6], z[7], bC1);
        #pragma unroll
        for (int k = 0; k < 4; ++k) {
            zz[pad(base0 + 8 * k)] = z[k];
            zz[pad(base1 + 8 * k)] = z[4 + k];
        }
    }
    __syncthreads();

    // ---- fused: fwd 4,2,1 ; Hilbert filter * 1/N ; inv 1,2,4 ----
    {
        const int base = 8 * t;
        #pragma unroll
        for (int k = 0; k < 8; ++k) z[k] = zz[pad(base + k)];
        const float cq = 0.70710678118654752f;
        const float2 W1  = make_float2(1.0f, 0.0f);
        const float2 W41 = make_float2(cq, -cq);
        const float2 W42 = make_float2(0.0f, -1.0f);
        const float2 W43 = make_float2(-cq, -cq);
        bf_f(z[0], z[4], W1);  bf_f(z[1], z[5], W41);
        bf_f(z[2], z[6], W42); bf_f(z[3], z[7], W43);
        bf_f(z[0], z[2], W1); bf_f(z[1], z[3], W42);
        bf_f(z[4], z[6], W1); bf_f(z[5], z[7], W42);
        bf_f(z[0], z[1], W1); bf_f(z[2], z[3], W1);
        bf_f(z[4], z[5], W1); bf_f(z[6], z[7], W1);
        const float inv = 1.0f / (float)Sv;
        #pragma unroll
        for (int k = 0; k < 8; ++k) {
            const int kk = (int)(__brev((unsigned)(base + k)) >> 21);   // logical index!
            const float m = (kk == 0 || kk == Sv / 2) ? inv : (kk < Sv / 2 ? 2.0f * inv : 0.0f);
            z[k].x *= m; z[k].y *= m;
        }
        bf_i(z[0], z[1], W1); bf_i(z[2], z[3], W1);
        bf_i(z[4], z[5], W1); bf_i(z[6], z[7], W1);
        bf_i(z[0], z[2], W1); bf_i(z[1], z[3], W42);
        bf_i(z[4], z[6], W1); bf_i(z[5], z[7], W42);
        bf_i(z[0], z[4], W1);  bf_i(z[1], z[5], W41);
        bf_i(z[2], z[6], W42); bf_i(z[3], z[7], W43);
        #pragma unroll
        for (int k = 0; k < 8; ++k) zz[pad(base + k)] = z[k];
    }
    __syncthreads();

    // ---- inv halves 8,16 (stride 8; two 4-sets) ----
    {
        const int r = t & 7, base0 = (t >> 3) * 32 + r, base1 = base0 + 1024;
        #pragma unroll
        for (int k = 0; k < 4; ++k) {
            z[k] = zz[pad(base0 + 8 * k)];
            z[4 + k] = zz[pad(base1 + 8 * k)];
        }
        bf_i(z[0], z[1], bC1); bf_i(z[2], z[3], bC1);
        bf_i(z[4], z[5], bC1); bf_i(z[6], z[7], bC1);
        const float2 wB = cmi(bC2);
        bf_i(z[0], z[2], bC2); bf_i(z[1], z[3], wB);
        bf_i(z[4], z[6], bC2); bf_i(z[5], z[7], wB);
        #pragma unroll
        for (int k = 0; k < 4; ++k) {
            zz[pad(base0 + 8 * k)] = z[k];
            zz[pad(base1 + 8 * k)] = z[4 + k];
        }
    }
    __syncthreads();

    // ---- inv halves 32,64,128 (stride 32) ----
    {
        const int r = t & 31, base = (t >> 5) * 256 + r;
        #pragma unroll
        for (int k = 0; k < 8; ++k) z[k] = zz[pad(base + 32 * k)];
        bf_i(z[0], z[1], bB1); bf_i(z[2], z[3], bB1);
        bf_i(z[4], z[5], bB1); bf_i(z[6], z[7], bB1);
        const float2 wB = cmi(bB2);
        bf_i(z[0], z[2], bB2); bf_i(z[1], z[3], wB);
        bf_i(z[4], z[6], bB2); bf_i(z[5], z[7], wB);
        const float2 w1 = cm1(bB4);
        bf_i(z[0], z[4], bB4);      bf_i(z[1], z[5], w1);
        bf_i(z[2], z[6], cmi(bB4)); bf_i(z[3], z[7], cmi(w1));
        #pragma unroll
        for (int k = 0; k < 8; ++k) zz[pad(base + 32 * k)] = z[k];
    }
    __syncthreads();

    // ---- inv halves 256,512,1024 (stride 256) + fused output write ----
    {
        #pragma unroll
        for (int k = 0; k < 8; ++k) z[k] = zz[pad(t + 256 * k)];
        bf_i(z[0], z[1], bA1); bf_i(z[2], z[3], bA1);
        bf_i(z[4], z[5], bA1); bf_i(z[6], z[7], bA1);
        const float2 wB = cmi(bA2);
        bf_i(z[0], z[2], bA2); bf_i(z[1], z[3], wB);
        bf_i(z[4], z[6], bA2); bf_i(z[5], z[7], wB);
        const float2 w1 = cm1(bA4);
        bf_i(z[0], z[4], bA4);      bf_i(z[1], z[5], w1);
        bf_i(z[2], z[6], cmi(bA4)); bf_i(z[3], z[7], cmi(w1));
        float* y0 = y + (size_t)c0 * Sv;
        float* y1 = y0 + Sv;
        #pragma unroll
        for (int k = 0; k < 8; ++k) {
            const int n = t + 256 * k;
            y0[n] = z[k].y - x1[n];   // H(x_a) = Im(w) - x_b
            y1[n] = x0[n] - z[k].x;   // H(x_b) = x_a - Re(w)
        }
    }
}

// ---------------------------------------------------------------------------
// Kernel 2: PLI negative-sign partial counts, TRIANGLE tiling (R8-identical).
// ---------------------------------------------------------------------------
__global__ __launch_bounds__(256) void pli_count_kernel(const float* __restrict__ x,
                                                        const float* __restrict__ y,
                                                        unsigned int* __restrict__ part) {
    __shared__ __align__(16) float xL[SSEG * ROWS];
    __shared__ __align__(16) float yL[SSEG * ROWS];
    const int blk = blockIdx.x;                 // b*NSEG + seg
    const int seg = blk & (NSEG - 1);
    const int b = blk >> 6;
    const int t = threadIdx.x;
    const float* xb = x + (size_t)b * Cv * Sv + seg * SSEG;
    const float* yb = y + (size_t)b * Cv * Sv + seg * SSEG;

    for (int e = t; e < Cv * SSEG; e += 256) {
        const int ch = e >> 5;
        const int s = e & (SSEG - 1);
        xL[s * ROWS + ch] = xb[(size_t)ch * Sv + s];
        yL[s * ROWS + ch] = yb[(size_t)ch * Sv + s];
    }
    __syncthreads();

    if (t < NTILE) {
        const int qi = t & 15;
        const int dq = t >> 4;                  // 0..8
        const int i0 = qi * 4;
        const int j0 = ((qi + dq) & 15) * 4;
        int neg[4][4] = {};

        #pragma unroll 4
        for (int s = 0; s < SSEG; ++s) {
            const float4 xi = *(const float4*)&xL[s * ROWS + i0];
            const float4 yi = *(const float4*)&yL[s * ROWS + i0];
            const float4 xj = *(const float4*)&xL[s * ROWS + j0];
            const float4 yj = *(const float4*)&yL[s * ROWS + j0];
            const float xia[4] = {xi.x, xi.y, xi.z, xi.w};
            const float yia[4] = {yi.x, yi.y, yi.z, yi.w};
            const float xja[4] = {xj.x, xj.y, xj.z, xj.w};
            const float yja[4] = {yj.x, yj.y, yj.z, yj.w};
            #pragma unroll
            for (int a = 0; a < 4; ++a) {
                #pragma unroll
                for (int c = 0; c < 4; ++c) {
                    const float cr = fmaf(yia[a], xja[c], -(xia[a] * yja[c]));
                    neg[a][c] += (int)(__float_as_uint(cr) >> 31);
                }
            }
        }

        unsigned int* Pb = part + ((size_t)blk * NTILE + t) * 4;
        unsigned int pk[4];
        #pragma unroll
        for (int a = 0; a < 4; ++a)
            pk[a] = (unsigned)neg[a][0] | ((unsigned)neg[a][1] << 8)
                  | ((unsigned)neg[a][2] << 16) | ((unsigned)neg[a][3] << 24);
        *(uint4*)Pb = make_uint4(pk[0], pk[1], pk[2], pk[3]);
    }
}

// ---------------------------------------------------------------------------
// Kernel 3: reduce triangle partials -> PLI (R8-identical).
// ---------------------------------------------------------------------------
__global__ __launch_bounds__(256) void finalize_kernel(const unsigned char* __restrict__ part,
                                                       float* __restrict__ out) {
    const int idx = blockIdx.x * 256 + threadIdx.x;   // 65536 = B*C*C
    const int b = idx >> 12;
    const int ij = idx & 4095;
    const int i = ij >> 6, j = ij & 63;
    const int qi = i >> 2, a = i & 3;
    const int qj = j >> 2, c = j & 3;
    const int g = (qj - qi) & 15;
    int byteoff;
    if (g <= 8) byteoff = (g * 16 + qi) * 16 + a * 4 + c;
    else        byteoff = ((16 - g) * 16 + qj) * 16 + c * 4 + a;
    const unsigned char* p = part + (size_t)b * NSEG * (NTILE * 16) + byteoff;
    int negsum = 0;
    #pragma unroll 8
    for (int s = 0; s < NSEG; ++s)
        negsum += (int)p[s * (NTILE * 16)];
    out[idx] = (i == j) ? 0.0f
                        : fabsf((float)Sv - 2.0f * (float)negsum) * (1.0f / (float)Sv);
}

extern "C" void kernel_launch(void* const* d_in, const int* in_sizes, int n_in,
                              void* d_out, int out_size, void* d_ws, size_t ws_size,
                              hipStream_t stream) {
    const float* x = (const float*)d_in[0];            // [B, C, S] fp32
    float* y = (float*)d_ws;                           // [B, C, S] fp32 (8 MB)
    unsigned int* part = (unsigned int*)((char*)d_ws + (size_t)Bv * Cv * Sv * sizeof(float));
    float* out = (float*)d_out;                        // [B, C, C] fp32

    hipLaunchKernelGGL(hilbert_kernel, dim3(Bv * Cv / 2), dim3(256), 0, stream, x, y);
    hipLaunchKernelGGL(pli_count_kernel, dim3(Bv * NSEG), dim3(256), 0, stream, x, y, part);
    hipLaunchKernelGGL(finalize_kernel, dim3(Bv * Cv * Cv / 256), dim3(256), 0, stream,
                       (const unsigned char*)part, out);
}